// Round 1
// baseline (861.591 us; speedup 1.0000x reference)
//
#include <hip/hip_runtime.h>
#include <cstdint>
#include <cstddef>

typedef __bf16 bf16;
typedef __attribute__((ext_vector_type(8))) bf16  bf16x8;
typedef __attribute__((ext_vector_type(4))) bf16  bf16x4;
typedef __attribute__((ext_vector_type(4))) float f32x4;

// Problem constants
#define B_SZ   2
#define T_SZ   32
#define H_SZ   18
#define W_SZ   32
#define DIM    1024
#define NHEAD  16
#define HDIM   64
#define E3     3072                  // 3*NHEAD*HDIM
#define M_TOT  36864                 // B*T*H*W
#define T_STRIDE 576                 // H_SZ*W_SZ rows per t step

// ---------------------------------------------------------------------------
// fp32 -> bf16 conversion (vectorized x4)
// ---------------------------------------------------------------------------
__global__ void taa_cvt_bf16(const float* __restrict__ s, bf16* __restrict__ d, int n4) {
    int i = blockIdx.x * 256 + threadIdx.x;
    if (i >= n4) return;
    float4 v = ((const float4*)s)[i];
    bf16x4 o;
    o.x = (bf16)v.x; o.y = (bf16)v.y; o.z = (bf16)v.z; o.w = (bf16)v.w;
    ((bf16x4*)d)[i] = o;
}

// ---------------------------------------------------------------------------
// async global->LDS 16B (wave-uniform base + lane*16 semantics)
// ---------------------------------------------------------------------------
__device__ __forceinline__ void async_copy_16(const bf16* g, bf16* l) {
    __builtin_amdgcn_global_load_lds((__attribute__((address_space(1))) void*)g,
                                     (__attribute__((address_space(3))) void*)l,
                                     16, 0, 0);
}

// ---------------------------------------------------------------------------
// C[M,N] = A[M,K] * B[N,K]^T  (both K-contiguous), bf16 in, fp32 accumulate.
// 128x128 block tile, BK=32, 256 threads = 4 waves, each wave 64x64 via
// 4x4 grid of mfma_f32_16x16x32_bf16. m97-style 2-barrier K loop.
// OUT_BF16: store bf16 C.  else: store fp32 C + bias[col].
// ---------------------------------------------------------------------------
template<bool OUT_BF16>
__global__ __launch_bounds__(256)
void taa_gemm_bt(const bf16* __restrict__ A, const bf16* __restrict__ B,
                 void* __restrict__ Cout, const float* __restrict__ bias,
                 int N, int K) {
    __shared__ __align__(16) bf16 sA[128 * 32];
    __shared__ __align__(16) bf16 sB[128 * 32];

    const int tid  = threadIdx.x;
    const int bm   = blockIdx.y * 128;
    const int bn   = blockIdx.x * 128;
    const int lane = tid & 63;
    const int wv   = tid >> 6;
    const int wm   = (wv >> 1) * 64;    // wave row offset within block tile
    const int wn   = (wv & 1) * 64;     // wave col offset
    const int fr   = lane & 15;         // fragment row (A) / col-row (B)
    const int fq   = lane >> 4;         // quad -> k offset = fq*8

    f32x4 acc[4][4];
#pragma unroll
    for (int i = 0; i < 4; i++)
#pragma unroll
        for (int j = 0; j < 4; j++) acc[i][j] = (f32x4){0.f, 0.f, 0.f, 0.f};

    // staging: thread tid covers LDS bytes [tid*16, tid*16+16) => row tid/4, col8 = (tid&3)*8
    const bf16* gA = A + (size_t)(bm + (tid >> 2)) * K + (tid & 3) * 8;
    const bf16* gB = B + (size_t)(bn + (tid >> 2)) * K + (tid & 3) * 8;
    bf16* lA = &sA[tid * 8];
    bf16* lB = &sB[tid * 8];
    const size_t rowskip = (size_t)64 * K;

    for (int kt = 0; kt < K; kt += 32) {
        __syncthreads();                       // LDS reuse guard
        async_copy_16(gA,            lA);
        async_copy_16(gA + rowskip,  lA + 2048);
        async_copy_16(gB,            lB);
        async_copy_16(gB + rowskip,  lB + 2048);
        gA += 32; gB += 32;
        __syncthreads();                       // compiler drains vmcnt(0) before barrier

        bf16x8 af[4], bfr[4];
#pragma unroll
        for (int i = 0; i < 4; i++)
            af[i] = *(const bf16x8*)&sA[(wm + i * 16 + fr) * 32 + fq * 8];
#pragma unroll
        for (int j = 0; j < 4; j++)
            bfr[j] = *(const bf16x8*)&sB[(wn + j * 16 + fr) * 32 + fq * 8];
#pragma unroll
        for (int i = 0; i < 4; i++)
#pragma unroll
            for (int j = 0; j < 4; j++)
                acc[i][j] = __builtin_amdgcn_mfma_f32_16x16x32_bf16(af[i], bfr[j], acc[i][j], 0, 0, 0);
    }

    // epilogue: C/D layout col=lane&15, row=(lane>>4)*4+reg  [verified m89/m91]
    if constexpr (OUT_BF16) {
        bf16* C = (bf16*)Cout;
#pragma unroll
        for (int i = 0; i < 4; i++)
#pragma unroll
            for (int j = 0; j < 4; j++)
#pragma unroll
                for (int r = 0; r < 4; r++) {
                    int row = bm + wm + i * 16 + fq * 4 + r;
                    int col = bn + wn + j * 16 + fr;
                    C[(size_t)row * N + col] = (bf16)acc[i][j][r];
                }
    } else {
        float* C = (float*)Cout;
#pragma unroll
        for (int i = 0; i < 4; i++)
#pragma unroll
            for (int j = 0; j < 4; j++)
#pragma unroll
                for (int r = 0; r < 4; r++) {
                    int row = bm + wm + i * 16 + fq * 4 + r;
                    int col = bn + wn + j * 16 + fr;
                    C[(size_t)row * N + col] = acc[i][j][r] + bias[col];
                }
    }
}

// ---------------------------------------------------------------------------
// Fused RoPE + causal attention for one (b,h,w,head): T=32, D=64, fp32 math.
// qkv layout: [m, e] with m=((b*32+t)*18+h)*32+w, e = {q:0,k:1024,v:2048}+head*64+d
// o layout: [m, head*64+d]  (bf16)
// ---------------------------------------------------------------------------
__global__ __launch_bounds__(256)
void taa_attn(const bf16* __restrict__ qkv, bf16* __restrict__ o) {
    __shared__ float sQ[32 * 65];
    __shared__ float sK[32 * 65];
    __shared__ float sV[32 * 65];
    __shared__ float sS[32 * 33];

    const int tid  = threadIdx.x;
    const int bid  = blockIdx.x;        // n*16 + head
    const int head = bid & 15;
    const int n    = bid >> 4;          // (b*18 + h)*32 + w
    const int w_sp = n & 31;
    const int h_sp = (n >> 5) % 18;
    const int b    = n / (18 * 32);
    const int m0   = (b * 32 * 18 + h_sp) * 32 + w_sp;   // row for t=0

    const int t  = tid >> 3;            // 0..31
    const int d0 = (tid & 7) * 8;       // 0..56

    // load q,k,v rows (8 elems each), fp32-ify, apply RoPE to q,k (d<32)
    {
        const size_t rb = (size_t)(m0 + t * T_STRIDE) * E3 + head * 64 + d0;
        bf16x8 qv = *(const bf16x8*)(qkv + rb);
        bf16x8 kv = *(const bf16x8*)(qkv + rb + 1024);
        bf16x8 vv = *(const bf16x8*)(qkv + rb + 2048);
        float qf[8], kf[8], vf[8];
#pragma unroll
        for (int j = 0; j < 8; j++) {
            qf[j] = (float)qv[j]; kf[j] = (float)kv[j]; vf[j] = (float)vv[j];
        }
        if (d0 < 32) {
#pragma unroll
            for (int p = 0; p < 4; p++) {
                const int fi = d0 / 2 + p;                    // pair index 0..15
                float freq = exp2f(-(float)fi * 0.830482024f); // 10000^(-fi/16)
                float ang  = (float)t * freq;
                float s, c;
                sincosf(ang, &s, &c);
                float a = qf[2 * p], bb = qf[2 * p + 1];
                qf[2 * p]     = a * c - bb * s;
                qf[2 * p + 1] = bb * c + a * s;
                a = kf[2 * p]; bb = kf[2 * p + 1];
                kf[2 * p]     = a * c - bb * s;
                kf[2 * p + 1] = bb * c + a * s;
            }
        }
#pragma unroll
        for (int j = 0; j < 8; j++) {
            sQ[t * 65 + d0 + j] = qf[j];
            sK[t * 65 + d0 + j] = kf[j];
            sV[t * 65 + d0 + j] = vf[j];
        }
    }
    __syncthreads();

    // scores: thread (r = tid/8, 4 cols) ; scale 1/sqrt(64)
    {
        const int r  = tid >> 3;
        const int c0 = (tid & 7) * 4;
        float a0 = 0.f, a1 = 0.f, a2 = 0.f, a3 = 0.f;
        for (int dd = 0; dd < 64; ++dd) {
            float q = sQ[r * 65 + dd];
            a0 += q * sK[(c0 + 0) * 65 + dd];
            a1 += q * sK[(c0 + 1) * 65 + dd];
            a2 += q * sK[(c0 + 2) * 65 + dd];
            a3 += q * sK[(c0 + 3) * 65 + dd];
        }
        sS[r * 33 + c0 + 0] = a0 * 0.125f;
        sS[r * 33 + c0 + 1] = a1 * 0.125f;
        sS[r * 33 + c0 + 2] = a2 * 0.125f;
        sS[r * 33 + c0 + 3] = a3 * 0.125f;
    }
    __syncthreads();

    // causal softmax, one thread per row (only c<=r ever read afterwards)
    if (tid < 32) {
        const int r = tid;
        float mx = -3.0e38f;
        for (int c = 0; c <= r; c++) mx = fmaxf(mx, sS[r * 33 + c]);
        float sum = 0.f;
        for (int c = 0; c <= r; c++) {
            float e = __expf(sS[r * 33 + c] - mx);
            sS[r * 33 + c] = e;
            sum += e;
        }
        float inv = 1.0f / sum;
        for (int c = 0; c <= r; c++) sS[r * 33 + c] *= inv;
    }
    __syncthreads();

    // O = P*V : thread (t, d0..d0+7)
    {
        float acc[8] = {0.f, 0.f, 0.f, 0.f, 0.f, 0.f, 0.f, 0.f};
        for (int k = 0; k <= t; k++) {
            float p = sS[t * 33 + k];
#pragma unroll
            for (int j = 0; j < 8; j++) acc[j] += p * sV[k * 65 + d0 + j];
        }
        bf16x8 ov;
#pragma unroll
        for (int j = 0; j < 8; j++) ov[j] = (bf16)acc[j];
        *(bf16x8*)(o + (size_t)(m0 + t * T_STRIDE) * DIM + head * 64 + d0) = ov;
    }
}

// ---------------------------------------------------------------------------
extern "C" void kernel_launch(void* const* d_in, const int* in_sizes, int n_in,
                              void* d_out, int out_size, void* d_ws, size_t ws_size,
                              hipStream_t stream) {
    const float* x     = (const float*)d_in[0];
    const float* w_qkv = (const float*)d_in[1];
    const float* w_out = (const float*)d_in[2];
    const float* b_out = (const float*)d_in[3];

    char* ws = (char*)d_ws;
    // workspace layout (bytes)
    bf16* x_b    = (bf16*)(ws + 0);            //  75,497,472  x as bf16
    bf16* wqkv_b = (bf16*)(ws + 75497472);     //   6,291,456
    bf16* wout_b = (bf16*)(ws + 81788928);     //   2,097,152
    bf16* qkv_b  = (bf16*)(ws + 83886080);     // 226,492,416  qkv [M,3072] bf16
    bf16* o_b    = (bf16*)(ws + 310378496);    //  75,497,472  o   [M,1024] bf16
                                               // total 385,875,968

    // convert inputs to bf16
    taa_cvt_bf16<<<(M_TOT * DIM / 4 + 255) / 256, 256, 0, stream>>>(x, x_b, M_TOT * DIM / 4);
    taa_cvt_bf16<<<(E3 * DIM / 4 + 255) / 256, 256, 0, stream>>>(w_qkv, wqkv_b, E3 * DIM / 4);
    taa_cvt_bf16<<<(DIM * DIM / 4 + 255) / 256, 256, 0, stream>>>(w_out, wout_b, DIM * DIM / 4);

    // QKV projection: [36864,3072] = x_b[36864,1024] * wqkv_b[3072,1024]^T
    taa_gemm_bt<true><<<dim3(E3 / 128, M_TOT / 128), 256, 0, stream>>>(
        x_b, wqkv_b, (void*)qkv_b, nullptr, E3, DIM);

    // fused RoPE + causal attention, one block per (b,h,w,head)
    taa_attn<<<1152 * 16, 256, 0, stream>>>(qkv_b, o_b);

    // output projection: d_out[36864,1024] = o_b * wout_b^T + b_out
    taa_gemm_bt<false><<<dim3(DIM / 128, M_TOT / 128), 256, 0, stream>>>(
        o_b, wout_b, d_out, b_out, DIM, DIM);
}

// Round 3
// 755.443 us; speedup vs baseline: 1.1405x; 1.1405x over previous
//
#include <hip/hip_runtime.h>
#include <cstdint>
#include <cstddef>

typedef __bf16 bf16;
typedef __attribute__((ext_vector_type(8))) bf16  bf16x8;
typedef __attribute__((ext_vector_type(4))) bf16  bf16x4;
typedef __attribute__((ext_vector_type(4))) float f32x4;

// Problem constants
#define B_SZ   2
#define T_SZ   32
#define H_SZ   18
#define W_SZ   32
#define DIM    1024
#define NHEAD  16
#define HDIM   64
#define E3     3072                  // 3*NHEAD*HDIM
#define M_TOT  36864                 // B*T*H*W
#define T_STRIDE 576                 // H_SZ*W_SZ rows per t step

// ---------------------------------------------------------------------------
// fp32 -> bf16 conversion (vectorized x4)
// ---------------------------------------------------------------------------
__global__ void taa_cvt_bf16(const float* __restrict__ s, bf16* __restrict__ d, int n4) {
    int i = blockIdx.x * 256 + threadIdx.x;
    if (i >= n4) return;
    float4 v = ((const float4*)s)[i];
    bf16x4 o;
    o.x = (bf16)v.x; o.y = (bf16)v.y; o.z = (bf16)v.z; o.w = (bf16)v.w;
    ((bf16x4*)d)[i] = o;
}

// ---------------------------------------------------------------------------
// async global->LDS 16B (wave-uniform base + lane*16 semantics)
// ---------------------------------------------------------------------------
__device__ __forceinline__ void async_copy_16(const bf16* g, bf16* l) {
    __builtin_amdgcn_global_load_lds((__attribute__((address_space(1))) void*)g,
                                     (__attribute__((address_space(3))) void*)l,
                                     16, 0, 0);
}

// ---------------------------------------------------------------------------
// C[M,N] = A[M,K] * B[N,K]^T  (both K-contiguous), bf16 in, fp32 accumulate.
// 128x128 block tile, BK=32, 256 threads = 4 waves, each wave 64x64 via
// 4x4 grid of mfma_f32_16x16x32_bf16.
// LDS bank-conflict fix: XOR-swizzle the 16B k-chunk by ((row>>1)&3), applied
// on the STAGING (global source chunk) side since global_load_lds destinations
// are fixed at lane*16; fragment reads un-swizzle with the same XOR. Swizzle
// index is invariant under tile offsets (wm, i*16, +64 rows: all ≡ 0 mod 8).
// ---------------------------------------------------------------------------
template<bool OUT_BF16>
__global__ __launch_bounds__(256)
void taa_gemm_bt(const bf16* __restrict__ A, const bf16* __restrict__ B,
                 void* __restrict__ Cout, const float* __restrict__ bias,
                 int N, int K) {
    __shared__ __align__(16) bf16 sA[128 * 32];
    __shared__ __align__(16) bf16 sB[128 * 32];

    const int tid  = threadIdx.x;
    const int bm   = blockIdx.y * 128;
    const int bn   = blockIdx.x * 128;
    const int lane = tid & 63;
    const int wv   = tid >> 6;
    const int wm   = (wv >> 1) * 64;    // wave row offset within block tile
    const int wn   = (wv & 1) * 64;     // wave col offset
    const int fr   = lane & 15;         // fragment row (A) / row of B^T
    const int fq   = lane >> 4;         // quad -> k chunk
    const int kswz = (fr >> 1) & 3;     // read-side XOR for bank spread

    f32x4 acc[4][4];
#pragma unroll
    for (int i = 0; i < 4; i++)
#pragma unroll
        for (int j = 0; j < 4; j++) acc[i][j] = (f32x4){0.f, 0.f, 0.f, 0.f};

    // staging: thread tid fills LDS bytes [tid*16, tid*16+16) = row tid/4, lds-chunk tid&3.
    // Global source chunk is XOR-swizzled so banks spread across rows.
    const int srow   = tid >> 2;
    const int schunk = (tid & 3) ^ ((srow >> 1) & 3);
    const bf16* gA = A + (size_t)(bm + srow) * K + schunk * 8;
    const bf16* gB = B + (size_t)(bn + srow) * K + schunk * 8;
    bf16* lA = &sA[tid * 8];
    bf16* lB = &sB[tid * 8];
    const size_t rowskip = (size_t)64 * K;

    for (int kt = 0; kt < K; kt += 32) {
        __syncthreads();                       // LDS reuse guard
        async_copy_16(gA,            lA);
        async_copy_16(gA + rowskip,  lA + 2048);
        async_copy_16(gB,            lB);
        async_copy_16(gB + rowskip,  lB + 2048);
        gA += 32; gB += 32;
        __syncthreads();                       // drains vmcnt(0) before barrier

        bf16x8 af[4], bfr[4];
#pragma unroll
        for (int i = 0; i < 4; i++)
            af[i] = *(const bf16x8*)&sA[(wm + i * 16 + fr) * 32 + (fq ^ kswz) * 8];
#pragma unroll
        for (int j = 0; j < 4; j++)
            bfr[j] = *(const bf16x8*)&sB[(wn + j * 16 + fr) * 32 + (fq ^ kswz) * 8];
#pragma unroll
        for (int i = 0; i < 4; i++)
#pragma unroll
            for (int j = 0; j < 4; j++)
                acc[i][j] = __builtin_amdgcn_mfma_f32_16x16x32_bf16(af[i], bfr[j], acc[i][j], 0, 0, 0);
    }

    // epilogue: C/D layout col=lane&15, row=(lane>>4)*4+reg  [verified m89/m91]
    if constexpr (OUT_BF16) {
        bf16* C = (bf16*)Cout;
#pragma unroll
        for (int i = 0; i < 4; i++)
#pragma unroll
            for (int j = 0; j < 4; j++)
#pragma unroll
                for (int r = 0; r < 4; r++) {
                    int row = bm + wm + i * 16 + fq * 4 + r;
                    int col = bn + wn + j * 16 + fr;
                    C[(size_t)row * N + col] = (bf16)acc[i][j][r];
                }
    } else {
        float* C = (float*)Cout;
#pragma unroll
        for (int i = 0; i < 4; i++)
#pragma unroll
            for (int j = 0; j < 4; j++)
#pragma unroll
                for (int r = 0; r < 4; r++) {
                    int row = bm + wm + i * 16 + fq * 4 + r;
                    int col = bn + wn + j * 16 + fr;
                    C[(size_t)row * N + col] = acc[i][j][r] + bias[col];
                }
    }
}

// ---------------------------------------------------------------------------
// MFMA attention: one 64-thread wave per (n, head). T=32, D=64.
// S = Q*K^T via 2x2 tiles of mfma_16x16x32 (K=64 -> 2 steps); softmax in
// registers (C-layout rows, shfl_xor across the 16-lane fr group); P round-
// trips through LDS into A-layout; O = P*V^T via 2x4 tiles (K=32 -> 1 step).
// qkv: [m, e]; o: [m, head*64+d], both bf16.
// ---------------------------------------------------------------------------
__global__ __launch_bounds__(64)
void taa_attn_mfma(const bf16* __restrict__ qkv, bf16* __restrict__ o) {
    __shared__ __align__(16) bf16 sQ[32 * 72];   // stride 72: +8 pad -> 2-way banks
    __shared__ __align__(16) bf16 sK[32 * 72];
    __shared__ __align__(16) bf16 sVt[64 * 40];  // V^T [d][t], stride 40
    __shared__ __align__(16) bf16 sP[32 * 40];   // P   [tq][tk], stride 40

    const int lane = threadIdx.x;
    const int bid  = blockIdx.x;        // n*16 + head
    const int head = bid & 15;
    const int n    = bid >> 4;          // (b*18 + h)*32 + w
    const int w_sp = n & 31;
    const int h_sp = (n >> 5) % 18;
    const int b    = n / (18 * 32);
    const int m0   = b * 18432 + h_sp * 32 + w_sp;   // row for t=0

    // ---- load Q,K (RoPE) and V (transposed) into LDS ----
    {
        const int tl = lane >> 3;          // 0..7
        const int dl = (lane & 7) * 8;     // 0..56
#pragma unroll
        for (int it = 0; it < 4; ++it) {
            const int t = it * 8 + tl;
            const size_t rb = (size_t)(m0 + t * T_STRIDE) * E3 + head * 64 + dl;
            bf16x8 q8 = *(const bf16x8*)(qkv + rb);
            bf16x8 k8 = *(const bf16x8*)(qkv + rb + 1024);
            bf16x8 v8 = *(const bf16x8*)(qkv + rb + 2048);
            float qf[8], kf[8];
#pragma unroll
            for (int j = 0; j < 8; j++) { qf[j] = (float)q8[j]; kf[j] = (float)k8[j]; }
            if (dl < 32) {
#pragma unroll
                for (int p = 0; p < 4; p++) {
                    const int fi = dl / 2 + p;                   // pair 0..15
                    float freq = exp2f(-(float)fi * 0.830482024f); // 10000^(-fi/16)
                    float ang  = (float)t * freq;
                    float s, c;
                    sincosf(ang, &s, &c);
                    float a = qf[2 * p], bb = qf[2 * p + 1];
                    qf[2 * p]     = a * c - bb * s;
                    qf[2 * p + 1] = bb * c + a * s;
                    a = kf[2 * p]; bb = kf[2 * p + 1];
                    kf[2 * p]     = a * c - bb * s;
                    kf[2 * p + 1] = bb * c + a * s;
                }
            }
            bf16x8 qo, ko;
#pragma unroll
            for (int j = 0; j < 8; j++) { qo[j] = (bf16)qf[j]; ko[j] = (bf16)kf[j]; }
            *(bf16x8*)&sQ[t * 72 + dl] = qo;
            *(bf16x8*)&sK[t * 72 + dl] = ko;
#pragma unroll
            for (int j = 0; j < 8; j++) sVt[(dl + j) * 40 + t] = v8[j];
        }
    }
    __syncthreads();

    const int fr = lane & 15;
    const int fq = lane >> 4;            // 0..3

    // ---- S = Q K^T, 2x2 tiles, K=64 ----
    f32x4 S[2][2];
#pragma unroll
    for (int mt = 0; mt < 2; mt++)
#pragma unroll
        for (int nt = 0; nt < 2; nt++) S[mt][nt] = (f32x4){0.f, 0.f, 0.f, 0.f};

    bf16x8 kb0[2], kb1[2];
#pragma unroll
    for (int nt = 0; nt < 2; nt++) {
        kb0[nt] = *(const bf16x8*)&sK[(nt * 16 + fr) * 72 + fq * 8];
        kb1[nt] = *(const bf16x8*)&sK[(nt * 16 + fr) * 72 + 32 + fq * 8];
    }
#pragma unroll
    for (int mt = 0; mt < 2; mt++) {
        bf16x8 a0 = *(const bf16x8*)&sQ[(mt * 16 + fr) * 72 + fq * 8];
        bf16x8 a1 = *(const bf16x8*)&sQ[(mt * 16 + fr) * 72 + 32 + fq * 8];
#pragma unroll
        for (int nt = 0; nt < 2; nt++) {
            S[mt][nt] = __builtin_amdgcn_mfma_f32_16x16x32_bf16(a0, kb0[nt], S[mt][nt], 0, 0, 0);
            S[mt][nt] = __builtin_amdgcn_mfma_f32_16x16x32_bf16(a1, kb1[nt], S[mt][nt], 0, 0, 0);
        }
    }

    // ---- causal softmax in registers ----
    // C-layout: row = mt*16 + fq*4 + r (query t), col = nt*16 + fr (key t)
    float P[2][2][4];
#pragma unroll
    for (int mt = 0; mt < 2; mt++) {
#pragma unroll
        for (int r = 0; r < 4; r++) {
            const int row = mt * 16 + fq * 4 + r;
            float s0 = S[mt][0][r] * 0.125f;
            float s1 = S[mt][1][r] * 0.125f;
            if (fr > row)      s0 = -1e30f;
            if (16 + fr > row) s1 = -1e30f;
            float mx = fmaxf(s0, s1);
#pragma unroll
            for (int mk = 1; mk <= 8; mk <<= 1) mx = fmaxf(mx, __shfl_xor(mx, mk, 64));
            float e0 = __expf(s0 - mx);
            float e1 = __expf(s1 - mx);
            float sm = e0 + e1;
#pragma unroll
            for (int mk = 1; mk <= 8; mk <<= 1) sm += __shfl_xor(sm, mk, 64);
            float inv = 1.0f / sm;
            P[mt][0][r] = e0 * inv;
            P[mt][1][r] = e1 * inv;
        }
    }

    // ---- P -> LDS (C-layout scatter), read back in A-layout ----
#pragma unroll
    for (int mt = 0; mt < 2; mt++)
#pragma unroll
        for (int nt = 0; nt < 2; nt++)
#pragma unroll
            for (int r = 0; r < 4; r++)
                sP[(mt * 16 + fq * 4 + r) * 40 + nt * 16 + fr] = (bf16)P[mt][nt][r];
    __syncthreads();

    // ---- O = P V, 2x4 tiles, K=32 ----
    f32x4 O[2][4];
#pragma unroll
    for (int mt = 0; mt < 2; mt++)
#pragma unroll
        for (int dt = 0; dt < 4; dt++) O[mt][dt] = (f32x4){0.f, 0.f, 0.f, 0.f};
#pragma unroll
    for (int mt = 0; mt < 2; mt++) {
        bf16x8 a = *(const bf16x8*)&sP[(mt * 16 + fr) * 40 + fq * 8];
#pragma unroll
        for (int dt = 0; dt < 4; dt++) {
            bf16x8 bv = *(const bf16x8*)&sVt[(dt * 16 + fr) * 40 + fq * 8];
            O[mt][dt] = __builtin_amdgcn_mfma_f32_16x16x32_bf16(a, bv, O[mt][dt], 0, 0, 0);
        }
    }

    // ---- write O: row t = mt*16+fq*4+r, col d = dt*16+fr ----
#pragma unroll
    for (int mt = 0; mt < 2; mt++)
#pragma unroll
        for (int dt = 0; dt < 4; dt++)
#pragma unroll
            for (int r = 0; r < 4; r++) {
                const int t = mt * 16 + fq * 4 + r;
                const int d = dt * 16 + fr;
                o[(size_t)(m0 + t * T_STRIDE) * DIM + head * 64 + d] = (bf16)O[mt][dt][r];
            }
}

// ---------------------------------------------------------------------------
extern "C" void kernel_launch(void* const* d_in, const int* in_sizes, int n_in,
                              void* d_out, int out_size, void* d_ws, size_t ws_size,
                              hipStream_t stream) {
    const float* x     = (const float*)d_in[0];
    const float* w_qkv = (const float*)d_in[1];
    const float* w_out = (const float*)d_in[2];
    const float* b_out = (const float*)d_in[3];

    char* ws = (char*)d_ws;
    // workspace layout (bytes)
    bf16* x_b    = (bf16*)(ws + 0);            //  75,497,472  x as bf16
    bf16* wqkv_b = (bf16*)(ws + 75497472);     //   6,291,456
    bf16* wout_b = (bf16*)(ws + 81788928);     //   2,097,152
    bf16* qkv_b  = (bf16*)(ws + 83886080);     // 226,492,416  qkv [M,3072] bf16
    bf16* o_b    = (bf16*)(ws + 310378496);    //  75,497,472  o   [M,1024] bf16
                                               // total 385,875,968

    // convert inputs to bf16
    taa_cvt_bf16<<<(M_TOT * DIM / 4 + 255) / 256, 256, 0, stream>>>(x, x_b, M_TOT * DIM / 4);
    taa_cvt_bf16<<<(E3 * DIM / 4 + 255) / 256, 256, 0, stream>>>(w_qkv, wqkv_b, E3 * DIM / 4);
    taa_cvt_bf16<<<(DIM * DIM / 4 + 255) / 256, 256, 0, stream>>>(w_out, wout_b, DIM * DIM / 4);

    // QKV projection: [36864,3072] = x_b[36864,1024] * wqkv_b[3072,1024]^T
    taa_gemm_bt<true><<<dim3(E3 / 128, M_TOT / 128), 256, 0, stream>>>(
        x_b, wqkv_b, (void*)qkv_b, nullptr, E3, DIM);

    // MFMA attention: one wave per (n, head)
    taa_attn_mfma<<<1152 * 16, 64, 0, stream>>>(qkv_b, o_b);

    // output projection: d_out[36864,1024] = o_b * wout_b^T + b_out
    taa_gemm_bt<false><<<dim3(DIM / 128, M_TOT / 128), 256, 0, stream>>>(
        o_b, wout_b, d_out, b_out, DIM, DIM);
}